// Round 5
// baseline (506.354 us; speedup 1.0000x reference)
//
#include <hip/hip_runtime.h>
#include <hip/hip_bf16.h>

#define NBATCH 16384

typedef float f32x4 __attribute__((ext_vector_type(4)));

__device__ __forceinline__ float clamp01(float x){ return fminf(fmaxf(x, 0.f), 1.f); }

// ============================================================================
// Phase 1: XCD-sliced embedding-bag gather.
// 16 column-slices of 16 floats (one 64B line per row-slice); slice footprint
// 40960*64B = 2.62 MB < 4MB per-XCD L2. blockIdx%8 -> XCD (round-robin
// heuristic); grid ordered so each XCD does slice c then slice c+8.
// Writes clipped, stm-swapped hidden (16384 x 512 f32) to ws.
// ============================================================================
#define P1_BLOCK 256
#define P1_SPB   64     // samples per block
#define P1_SPW   16     // samples per wave
// blocks per slice = 16384/64 = 256; grid = 16*256 = 4096

__global__ __launch_bounds__(P1_BLOCK, 8) void nnue_gather(
    const int* __restrict__ wi, const int* __restrict__ bi,
    const float* __restrict__ stm,
    const float* __restrict__ ftw, const float* __restrict__ ftb,
    float* __restrict__ hid)
{
    __shared__ int idx_s[P1_SPB * 64];

    const int g     = blockIdx.x;
    const int xcd   = g & 7;
    const int o     = g >> 3;                // 0..511 per XCD
    const int slice = xcd + ((o >> 8) << 3); // first 256 blocks: slice=xcd, then xcd+8
    const int chunk = o & 255;
    const int sbase = chunk * P1_SPB;
    const int tid   = threadIdx.x;

    // stage 64 samples' indices (white 0..31, black 32..63) — nontemporal
    for (int p = tid; p < P1_SPB * 64; p += P1_BLOCK) {
        int sl = p >> 6, q = p & 63;
        int v = (q < 32) ? __builtin_nontemporal_load(&wi[(sbase + sl) * 32 + q])
                         : __builtin_nontemporal_load(&bi[(sbase + sl) * 32 + (q - 32)]);
        idx_s[p] = v;
    }
    __syncthreads();

    const int lane = tid & 63;
    const int wv   = tid >> 6;
    const int h    = lane >> 5;       // 0 = white, 1 = black
    const int sub  = lane & 31;
    const int r    = sub >> 2;        // row group 0..7
    const int f    = sub & 3;         // float4 index within 16-dim slice

    const float4 fb = *(const float4*)(ftb + slice * 16 + f * 4);
    const float* tbl = ftw + slice * 16 + f * 4;

    #pragma unroll 2
    for (int i = 0; i < P1_SPW; ++i) {
        const int sl = wv * P1_SPW + i;
        const int s  = sbase + sl;
        const int* ip = &idx_s[sl * 64 + h * 32 + r];

        float a0 = 0.f, a1 = 0.f, a2 = 0.f, a3 = 0.f;
        #pragma unroll
        for (int it = 0; it < 4; ++it) {
            int row = ip[it * 8];                         // LDS broadcast (2-way: free)
            float4 v = *(const float4*)(tbl + row * 256); // one 64B line per 16 rows/wave
            a0 += v.x; a1 += v.y; a2 += v.z; a3 += v.w;
        }
        // reduce the 8 row-groups (sub bits 2..4): stays within color half
        #pragma unroll
        for (int d = 4; d <= 16; d <<= 1) {
            a0 += __shfl_xor(a0, d, 64);
            a1 += __shfl_xor(a1, d, 64);
            a2 += __shfl_xor(a2, d, 64);
            a3 += __shfl_xor(a3, d, 64);
        }
        a0 = clamp01(a0 + fb.x);
        a1 = clamp01(a1 + fb.y);
        a2 = clamp01(a2 + fb.z);
        a3 = clamp01(a3 + fb.w);

        const bool wf = stm[s] > 0.5f;                 // broadcast load
        const int off = ((h == 0) == wf) ? 0 : 256;    // stm swap at write time
        if (r == 0) {
            f32x4 ov = { a0, a1, a2, a3 };
            __builtin_nontemporal_store(ov,
                (f32x4*)(hid + (size_t)s * 512 + off + slice * 16 + f * 4));
        }
    }
}

// ============================================================================
// Phase 2: MLP. l1w (32x512 f32 = exactly 64 KB) in static LDS; lane owns
// 4 lo-dims + 4 hi-dims; 2-sample register blocking shares each ds_read_b128.
// ============================================================================
#define P2_BLOCK 512
#define P2_SPB   64     // samples per block -> grid 256

__global__ __launch_bounds__(P2_BLOCK, 4) void nnue_mlp(
    const float* __restrict__ hid,
    const float* __restrict__ l1w, const float* __restrict__ l1b,
    const float* __restrict__ l2w, const float* __restrict__ l2b,
    const float* __restrict__ l3w, const float* __restrict__ l3b,
    float* __restrict__ out)
{
    __shared__ __align__(16) float w_s[32 * 512];      // exactly 64 KB

    const int tid = threadIdx.x;
    {
        const float4* src = (const float4*)l1w;        // 4096 float4
        float4* dst = (float4*)w_s;
        #pragma unroll
        for (int i = 0; i < 8; ++i) dst[tid + i * P2_BLOCK] = src[tid + i * P2_BLOCK];
    }
    __syncthreads();

    const int lane = tid & 63;
    const int wv   = tid >> 6;
    const int j2   = lane & 31;
    const int sbase = blockIdx.x * P2_SPB + wv * 8;

    // per-lane persistent small weights
    float l2row[32];
    #pragma unroll
    for (int i = 0; i < 32; ++i) l2row[i] = l2w[j2 * 32 + i];
    const float l2b_j = l2b[j2];
    const float l3w_j = l3w[j2];
    const float l3b0  = l3b[0];

    for (int k = 0; k < 4; ++k) {
        const int s0 = sbase + 2 * k;
        const int s1 = s0 + 1;

        float4 h0l = *(const float4*)(hid + (size_t)s0 * 512 + lane * 4);
        float4 h0h = *(const float4*)(hid + (size_t)s0 * 512 + 256 + lane * 4);
        float4 h1l = *(const float4*)(hid + (size_t)s1 * 512 + lane * 4);
        float4 h1h = *(const float4*)(hid + (size_t)s1 * 512 + 256 + lane * 4);

        float p0[32], p1[32];
        #pragma unroll
        for (int o = 0; o < 32; ++o) {
            float4 wl = *(const float4*)&w_s[o * 512 + lane * 4];
            float4 wh = *(const float4*)&w_s[o * 512 + 256 + lane * 4];
            p0[o] = h0l.x*wl.x + h0l.y*wl.y + h0l.z*wl.z + h0l.w*wl.w
                  + h0h.x*wh.x + h0h.y*wh.y + h0h.z*wh.z + h0h.w*wh.w;
            p1[o] = h1l.x*wl.x + h1l.y*wl.y + h1l.z*wl.z + h1l.w*wl.w
                  + h1h.x*wh.x + h1h.y*wh.y + h1h.z*wh.z + h1h.w*wh.w;
        }
        #pragma unroll
        for (int o = 0; o < 32; ++o) {
            #pragma unroll
            for (int d = 1; d < 64; d <<= 1) {
                p0[o] += __shfl_xor(p0[o], d, 64);
                p1[o] += __shfl_xor(p1[o], d, 64);
            }
        }
        float a20 = l2b_j, a21 = l2b_j;
        #pragma unroll
        for (int i = 0; i < 32; ++i) {
            float b = l1b[i];                          // uniform -> scalar load
            a20 += clamp01(p0[i] + b) * l2row[i];
            a21 += clamp01(p1[i] + b) * l2row[i];
        }
        float x20 = clamp01(a20), x21 = clamp01(a21);

        float r0 = x20 * l3w_j, r1 = x21 * l3w_j;
        #pragma unroll
        for (int d = 1; d < 32; d <<= 1) {
            r0 += __shfl_xor(r0, d, 64);
            r1 += __shfl_xor(r1, d, 64);
        }
        if (lane == 0) {
            out[s0] = r0 + l3b0;
            out[s1] = r1 + l3b0;
        }
    }
}

// ============================================================================
// Fallback: proven monolithic kernel (round 2/3) if ws is too small.
// ============================================================================
#define WPB 8
#define BLOCK 512

__global__ __launch_bounds__(BLOCK, 8) void nnue_fwd_f32(
    const int* __restrict__ wi, const int* __restrict__ bi,
    const float* __restrict__ stm,
    const float* __restrict__ ftw, const float* __restrict__ ftb,
    const float* __restrict__ l1w, const float* __restrict__ l1b,
    const float* __restrict__ l2w, const float* __restrict__ l2b,
    const float* __restrict__ l3w, const float* __restrict__ l3b,
    float* __restrict__ out)
{
    __shared__ __align__(16) float l1w_s[16*512];
    __shared__ float l2w_s[32*33];
    __shared__ float l1b_s[32], l2b_s[32], l3w_s[32];
    __shared__ int idx_s[WPB][64];

    const int tid  = threadIdx.x;
    const int lane = tid & 63;
    const int wv   = tid >> 6;
    const int s    = blockIdx.x * WPB + wv;

    {
        const float4* src = (const float4*)l1w;
        float4* dst = (float4*)l1w_s;
        #pragma unroll
        for (int i = 0; i < 4; ++i) dst[tid + i*BLOCK] = src[tid + i*BLOCK];
    }
    for (int i = tid; i < 1024; i += BLOCK)
        l2w_s[(i >> 5)*33 + (i & 31)] = l2w[i];
    if (tid < 32) {
        l1b_s[tid] = l1b[tid];
        l2b_s[tid] = l2b[tid];
        l3w_s[tid] = l3w[tid];
    }
    {
        int bse = s*32 + (lane & 31);
        idx_s[wv][lane] = (lane < 32) ? wi[bse] : bi[bse];
    }
    __syncthreads();

    const int chunk = lane & 31;
    const int hsel  = lane & 32;

    float acc[8];
    {
        float4 a = *(const float4*)(ftb + chunk*8);
        float4 b = *(const float4*)(ftb + chunk*8 + 4);
        acc[0]=a.x; acc[1]=a.y; acc[2]=a.z; acc[3]=a.w;
        acc[4]=b.x; acc[5]=b.y; acc[6]=b.z; acc[7]=b.w;
    }
    #pragma unroll 8
    for (int j = 0; j < 32; ++j) {
        int row = idx_s[wv][j + hsel];
        const float* rp = ftw + (size_t)row*256 + chunk*8;
        float4 a = *(const float4*)rp;
        float4 b = *(const float4*)(rp + 4);
        acc[0]+=a.x; acc[1]+=a.y; acc[2]+=a.z; acc[3]+=a.w;
        acc[4]+=b.x; acc[5]+=b.y; acc[6]+=b.z; acc[7]+=b.w;
    }
    #pragma unroll
    for (int k = 0; k < 8; ++k) acc[k] = clamp01(acc[k]);

    const bool wf = stm[s] > 0.5f;
    float h[8];
    #pragma unroll
    for (int k = 0; k < 8; ++k) {
        float x = __shfl_xor(acc[k], 32, 64);
        h[k] = wf ? acc[k] : x;
    }

    float p[32];
    #pragma unroll
    for (int o = 0; o < 16; ++o) {
        float4 wa = *(const float4*)&l1w_s[o*512 + lane*8];
        float4 wb = *(const float4*)&l1w_s[o*512 + lane*8 + 4];
        p[o] = h[0]*wa.x + h[1]*wa.y + h[2]*wa.z + h[3]*wa.w
             + h[4]*wb.x + h[5]*wb.y + h[6]*wb.z + h[7]*wb.w;
    }
    __syncthreads();
    {
        const float4* src = (const float4*)l1w;
        float4* dst = (float4*)l1w_s;
        #pragma unroll
        for (int i = 0; i < 4; ++i) dst[tid + i*BLOCK] = src[2048 + tid + i*BLOCK];
    }
    __syncthreads();
    #pragma unroll
    for (int o = 0; o < 16; ++o) {
        float4 wa = *(const float4*)&l1w_s[o*512 + lane*8];
        float4 wb = *(const float4*)&l1w_s[o*512 + lane*8 + 4];
        p[16+o] = h[0]*wa.x + h[1]*wa.y + h[2]*wa.z + h[3]*wa.w
                + h[4]*wb.x + h[5]*wb.y + h[6]*wb.z + h[7]*wb.w;
    }
    #pragma unroll
    for (int o = 0; o < 32; ++o) {
        #pragma unroll
        for (int d = 1; d < 64; d <<= 1)
            p[o] += __shfl_xor(p[o], d, 64);
    }
    float x1[32];
    #pragma unroll
    for (int o = 0; o < 32; ++o) x1[o] = clamp01(p[o] + l1b_s[o]);

    const int j2 = lane & 31;
    float a2 = l2b_s[j2];
    #pragma unroll
    for (int i = 0; i < 32; ++i) a2 += x1[i] * l2w_s[j2*33 + i];
    float x2 = clamp01(a2);

    float r = x2 * l3w_s[j2];
    #pragma unroll
    for (int d = 16; d >= 1; d >>= 1) r += __shfl_xor(r, d, 64);

    if (lane == 0) out[s] = r + l3b[0];
}

extern "C" void kernel_launch(void* const* d_in, const int* in_sizes, int n_in,
                              void* d_out, int out_size, void* d_ws, size_t ws_size,
                              hipStream_t stream)
{
    const int*   wi  = (const int*)d_in[0];
    const int*   bi  = (const int*)d_in[2];
    const float* stm = (const float*)d_in[4];
    const float* ftw = (const float*)d_in[5];
    const float* ftb = (const float*)d_in[6];
    const float* l1w = (const float*)d_in[7];
    const float* l1b = (const float*)d_in[8];
    const float* l2w = (const float*)d_in[9];
    const float* l2b = (const float*)d_in[10];
    const float* l3w = (const float*)d_in[11];
    const float* l3b = (const float*)d_in[12];

    const size_t need = (size_t)NBATCH * 512 * sizeof(float);   // 33.5 MB
    if (ws_size >= need) {
        float* hid = (float*)d_ws;
        nnue_gather<<<dim3(4096), dim3(P1_BLOCK), 0, stream>>>(
            wi, bi, stm, ftw, ftb, hid);
        nnue_mlp<<<dim3(NBATCH / P2_SPB), dim3(P2_BLOCK), 0, stream>>>(
            hid, l1w, l1b, l2w, l2b, l3w, l3b, (float*)d_out);
    } else {
        nnue_fwd_f32<<<dim3(NBATCH / WPB), dim3(BLOCK), 0, stream>>>(
            wi, bi, stm, ftw, ftb, l1w, l1b, l2w, l2b, l3w, l3b,
            (float*)d_out);
    }
}

// Round 6
// 185.541 us; speedup vs baseline: 2.7291x; 2.7291x over previous
//
#include <hip/hip_runtime.h>
#include <hip/hip_bf16.h>

#define NBATCH 16384
#define WPB 4          // waves (samples) per block
#define BLOCK 256      // R2-proven config: 38.4 KB LDS -> 4 blocks/CU

typedef unsigned int u32;
typedef unsigned short u16;

__device__ __forceinline__ float clamp01(float x){ return fminf(fmaxf(x, 0.f), 1.f); }
__device__ __forceinline__ float bflo(u32 u){ return __uint_as_float(u << 16); }
__device__ __forceinline__ float bfhi(u32 u){ return __uint_as_float(u & 0xFFFF0000u); }

// round-to-nearest-even f32 -> bf16 (raw u16)
__device__ __forceinline__ u16 f2bf(float f){
    u32 u = __float_as_uint(f);
    u = u + 0x7FFFu + ((u >> 16) & 1u);
    return (u16)(u >> 16);
}

// ============================================================================
// Phase 0: convert ft_w (40960x256 f32, 40 MB) -> bf16 table in ws (20 MB).
// Streaming, ~60 MB HBM traffic, ~10 us.
// ============================================================================
__global__ __launch_bounds__(256) void convert_ftw(
    const float* __restrict__ src, u16* __restrict__ dst, int n4)
{
    int i = blockIdx.x * blockDim.x + threadIdx.x;
    const int stride = gridDim.x * blockDim.x;
    for (; i < n4; i += stride) {
        float4 v = ((const float4*)src)[i];
        ushort4 o;
        o.x = f2bf(v.x); o.y = f2bf(v.y); o.z = f2bf(v.z); o.w = f2bf(v.w);
        ((ushort4*)dst)[i] = o;
    }
}

// ============================================================================
// Main kernel: R2 monolithic structure, gather from bf16 table (16 B/lane/row,
// half the L2-miss bytes of the f32 table). f32 accumulate + f32 MLP.
// ============================================================================
__global__ __launch_bounds__(BLOCK, 4) void nnue_fwd_bf16tab(
    const int* __restrict__ wi, const int* __restrict__ bi,
    const float* __restrict__ stm,
    const u16* __restrict__ ftw_bf, const float* __restrict__ ftb,
    const float* __restrict__ l1w, const float* __restrict__ l1b,
    const float* __restrict__ l2w, const float* __restrict__ l2b,
    const float* __restrict__ l3w, const float* __restrict__ l3b,
    float* __restrict__ out)
{
    __shared__ __align__(16) float l1w_s[16*512];   // 32 KB: half of l1_w per pass
    __shared__ float l2w_s[32*33];                  // +1 pad rows
    __shared__ float l1b_s[32], l2b_s[32], l3w_s[32];
    __shared__ int idx_s[WPB][64];

    const int tid  = threadIdx.x;
    const int lane = tid & 63;
    const int wv   = tid >> 6;
    const int s    = blockIdx.x * WPB + wv;        // sample id

    // ---- stage small weights + l1 pass-1 (rows 0..15) ----
    {
        const float4* src = (const float4*)l1w;    // 16384 floats = 4096 float4
        float4* dst = (float4*)l1w_s;
        #pragma unroll
        for (int i = 0; i < 8; ++i) dst[tid + i*BLOCK] = src[tid + i*BLOCK];
    }
    for (int i = tid; i < 1024; i += BLOCK)
        l2w_s[(i >> 5)*33 + (i & 31)] = l2w[i];
    if (tid < 32) {
        l1b_s[tid] = l1b[tid];
        l2b_s[tid] = l2b[tid];
        l3w_s[tid] = l3w[tid];
    }
    {   // lanes 0-31: white idx, lanes 32-63: black idx
        int bse = s*32 + (lane & 31);
        idx_s[wv][lane] = (lane < 32) ? wi[bse] : bi[bse];
    }
    __syncthreads();

    const int chunk = lane & 31;   // this lane's dims: chunk*8 .. chunk*8+7
    const int hsel  = lane & 32;   // 0 = white half-wave, 32 = black

    // ---- embedding bag: init with ft_b (f32), accumulate 32 bf16 rows ----
    float acc[8];
    {
        float4 a = *(const float4*)(ftb + chunk*8);
        float4 b = *(const float4*)(ftb + chunk*8 + 4);
        acc[0]=a.x; acc[1]=a.y; acc[2]=a.z; acc[3]=a.w;
        acc[4]=b.x; acc[5]=b.y; acc[6]=b.z; acc[7]=b.w;
    }
    #pragma unroll 8
    for (int j = 0; j < 32; ++j) {
        int row = idx_s[wv][j + hsel];             // 2-addr broadcast, free
        uint4 v = *(const uint4*)(ftw_bf + (size_t)row*256 + chunk*8);  // 16 B
        acc[0]+=bflo(v.x); acc[1]+=bfhi(v.x); acc[2]+=bflo(v.y); acc[3]+=bfhi(v.y);
        acc[4]+=bflo(v.z); acc[5]+=bfhi(v.z); acc[6]+=bflo(v.w); acc[7]+=bfhi(v.w);
    }
    #pragma unroll
    for (int k = 0; k < 8; ++k) acc[k] = clamp01(acc[k]);

    // ---- stm swap: lane ends up holding hidden[lane*8 .. lane*8+7] ----
    const bool wf = stm[s] > 0.5f;
    float h[8];
    #pragma unroll
    for (int k = 0; k < 8; ++k) {
        float x = __shfl_xor(acc[k], 32, 64);
        h[k] = wf ? acc[k] : x;
    }

    // ---- l1 pass 1: outputs 0..15 ----
    float p[32];
    #pragma unroll
    for (int o = 0; o < 16; ++o) {
        float4 wa = *(const float4*)&l1w_s[o*512 + lane*8];
        float4 wb = *(const float4*)&l1w_s[o*512 + lane*8 + 4];
        p[o] = h[0]*wa.x + h[1]*wa.y + h[2]*wa.z + h[3]*wa.w
             + h[4]*wb.x + h[5]*wb.y + h[6]*wb.z + h[7]*wb.w;
    }
    __syncthreads();   // all waves done reading pass-1 weights

    // ---- stage l1 pass-2 (rows 16..31) ----
    {
        const float4* src = (const float4*)l1w;
        float4* dst = (float4*)l1w_s;
        #pragma unroll
        for (int i = 0; i < 8; ++i) dst[tid + i*BLOCK] = src[2048 + tid + i*BLOCK];
    }
    __syncthreads();

    #pragma unroll
    for (int o = 0; o < 16; ++o) {
        float4 wa = *(const float4*)&l1w_s[o*512 + lane*8];
        float4 wb = *(const float4*)&l1w_s[o*512 + lane*8 + 4];
        p[16+o] = h[0]*wa.x + h[1]*wa.y + h[2]*wa.z + h[3]*wa.w
                + h[4]*wb.x + h[5]*wb.y + h[6]*wb.z + h[7]*wb.w;
    }

    // ---- full 64-lane butterfly: every lane gets all 32 sums ----
    #pragma unroll
    for (int o = 0; o < 32; ++o) {
        #pragma unroll
        for (int d = 1; d < 64; d <<= 1)
            p[o] += __shfl_xor(p[o], d, 64);
    }
    float x1[32];
    #pragma unroll
    for (int o = 0; o < 32; ++o) x1[o] = clamp01(p[o] + l1b_s[o]);

    // ---- l2: lane j (dup at j+32) owns output j ----
    const int j2 = lane & 31;
    float a2 = l2b_s[j2];
    #pragma unroll
    for (int i = 0; i < 32; ++i) a2 += x1[i] * l2w_s[j2*33 + i];
    float x2 = clamp01(a2);

    // ---- l3: reduce 32 outputs within each half-wave ----
    float r = x2 * l3w_s[j2];
    #pragma unroll
    for (int d = 16; d >= 1; d >>= 1) r += __shfl_xor(r, d, 64);

    if (lane == 0) out[s] = r + l3b[0];
}

// ============================================================================
// Fallback: proven R2 monolithic f32 kernel (if ws too small for bf16 table).
// ============================================================================
__global__ __launch_bounds__(BLOCK, 4) void nnue_fwd_f32(
    const int* __restrict__ wi, const int* __restrict__ bi,
    const float* __restrict__ stm,
    const float* __restrict__ ftw, const float* __restrict__ ftb,
    const float* __restrict__ l1w, const float* __restrict__ l1b,
    const float* __restrict__ l2w, const float* __restrict__ l2b,
    const float* __restrict__ l3w, const float* __restrict__ l3b,
    float* __restrict__ out)
{
    __shared__ __align__(16) float l1w_s[16*512];
    __shared__ float l2w_s[32*33];
    __shared__ float l1b_s[32], l2b_s[32], l3w_s[32];
    __shared__ int idx_s[WPB][64];

    const int tid  = threadIdx.x;
    const int lane = tid & 63;
    const int wv   = tid >> 6;
    const int s    = blockIdx.x * WPB + wv;

    {
        const float4* src = (const float4*)l1w;
        float4* dst = (float4*)l1w_s;
        #pragma unroll
        for (int i = 0; i < 8; ++i) dst[tid + i*BLOCK] = src[tid + i*BLOCK];
    }
    for (int i = tid; i < 1024; i += BLOCK)
        l2w_s[(i >> 5)*33 + (i & 31)] = l2w[i];
    if (tid < 32) {
        l1b_s[tid] = l1b[tid];
        l2b_s[tid] = l2b[tid];
        l3w_s[tid] = l3w[tid];
    }
    {
        int bse = s*32 + (lane & 31);
        idx_s[wv][lane] = (lane < 32) ? wi[bse] : bi[bse];
    }
    __syncthreads();

    const int chunk = lane & 31;
    const int hsel  = lane & 32;

    float acc[8];
    {
        float4 a = *(const float4*)(ftb + chunk*8);
        float4 b = *(const float4*)(ftb + chunk*8 + 4);
        acc[0]=a.x; acc[1]=a.y; acc[2]=a.z; acc[3]=a.w;
        acc[4]=b.x; acc[5]=b.y; acc[6]=b.z; acc[7]=b.w;
    }
    #pragma unroll 8
    for (int j = 0; j < 32; ++j) {
        int row = idx_s[wv][j + hsel];
        const float* rp = ftw + (size_t)row*256 + chunk*8;
        float4 a = *(const float4*)rp;
        float4 b = *(const float4*)(rp + 4);
        acc[0]+=a.x; acc[1]+=a.y; acc[2]+=a.z; acc[3]+=a.w;
        acc[4]+=b.x; acc[5]+=b.y; acc[6]+=b.z; acc[7]+=b.w;
    }
    #pragma unroll
    for (int k = 0; k < 8; ++k) acc[k] = clamp01(acc[k]);

    const bool wf = stm[s] > 0.5f;
    float h[8];
    #pragma unroll
    for (int k = 0; k < 8; ++k) {
        float x = __shfl_xor(acc[k], 32, 64);
        h[k] = wf ? acc[k] : x;
    }

    float p[32];
    #pragma unroll
    for (int o = 0; o < 16; ++o) {
        float4 wa = *(const float4*)&l1w_s[o*512 + lane*8];
        float4 wb = *(const float4*)&l1w_s[o*512 + lane*8 + 4];
        p[o] = h[0]*wa.x + h[1]*wa.y + h[2]*wa.z + h[3]*wa.w
             + h[4]*wb.x + h[5]*wb.y + h[6]*wb.z + h[7]*wb.w;
    }
    __syncthreads();
    {
        const float4* src = (const float4*)l1w;
        float4* dst = (float4*)l1w_s;
        #pragma unroll
        for (int i = 0; i < 8; ++i) dst[tid + i*BLOCK] = src[2048 + tid + i*BLOCK];
    }
    __syncthreads();
    #pragma unroll
    for (int o = 0; o < 16; ++o) {
        float4 wa = *(const float4*)&l1w_s[o*512 + lane*8];
        float4 wb = *(const float4*)&l1w_s[o*512 + lane*8 + 4];
        p[16+o] = h[0]*wa.x + h[1]*wa.y + h[2]*wa.z + h[3]*wa.w
                + h[4]*wb.x + h[5]*wb.y + h[6]*wb.z + h[7]*wb.w;
    }
    #pragma unroll
    for (int o = 0; o < 32; ++o) {
        #pragma unroll
        for (int d = 1; d < 64; d <<= 1)
            p[o] += __shfl_xor(p[o], d, 64);
    }
    float x1[32];
    #pragma unroll
    for (int o = 0; o < 32; ++o) x1[o] = clamp01(p[o] + l1b_s[o]);

    const int j2 = lane & 31;
    float a2 = l2b_s[j2];
    #pragma unroll
    for (int i = 0; i < 32; ++i) a2 += x1[i] * l2w_s[j2*33 + i];
    float x2 = clamp01(a2);

    float r = x2 * l3w_s[j2];
    #pragma unroll
    for (int d = 16; d >= 1; d >>= 1) r += __shfl_xor(r, d, 64);

    if (lane == 0) out[s] = r + l3b[0];
}

extern "C" void kernel_launch(void* const* d_in, const int* in_sizes, int n_in,
                              void* d_out, int out_size, void* d_ws, size_t ws_size,
                              hipStream_t stream)
{
    const int*   wi  = (const int*)d_in[0];
    const int*   bi  = (const int*)d_in[2];
    const float* stm = (const float*)d_in[4];
    const float* ftw = (const float*)d_in[5];
    const float* ftb = (const float*)d_in[6];
    const float* l1w = (const float*)d_in[7];
    const float* l1b = (const float*)d_in[8];
    const float* l2w = (const float*)d_in[9];
    const float* l2b = (const float*)d_in[10];
    const float* l3w = (const float*)d_in[11];
    const float* l3b = (const float*)d_in[12];

    const size_t tab_elems = (size_t)40960 * 256;              // 10.5 M
    const size_t need = tab_elems * sizeof(u16);               // 20 MB
    if (ws_size >= need) {
        u16* ftw_bf = (u16*)d_ws;
        convert_ftw<<<dim3(4096), dim3(256), 0, stream>>>(
            ftw, ftw_bf, (int)(tab_elems / 4));
        nnue_fwd_bf16tab<<<dim3(NBATCH / WPB), dim3(BLOCK), 0, stream>>>(
            wi, bi, stm, ftw_bf, ftb, l1w, l1b, l2w, l2b, l3w, l3b,
            (float*)d_out);
    } else {
        nnue_fwd_f32<<<dim3(NBATCH / WPB), dim3(BLOCK), 0, stream>>>(
            wi, bi, stm, ftw, ftb, l1w, l1b, l2w, l2b, l3w, l3b,
            (float*)d_out);
    }
}